// Round 10
// baseline (246.529 us; speedup 1.0000x reference)
//
#include <hip/hip_runtime.h>
#include <hip/hip_cooperative_groups.h>
#include <math.h>

namespace cg = cooperative_groups;

#define Dk 256
#define Pk 32
#define Bk 128

using f32x4    = __attribute__((ext_vector_type(4))) float;
using short8   = __attribute__((ext_vector_type(8))) short;
using short4v  = __attribute__((ext_vector_type(4))) short;
using ushort4v = __attribute__((ext_vector_type(4))) unsigned short;

static __device__ __forceinline__ unsigned short bf16_rtne(float x) {
    unsigned u = __float_as_uint(x);
    return (unsigned short)((u + 0x7fffu + ((u >> 16) & 1u)) >> 16);
}
static __device__ __forceinline__ float bf16_back(unsigned short h) {
    return __uint_as_float(((unsigned)h) << 16);
}
static __device__ __forceinline__ void split2(float x, unsigned short& h, unsigned short& l) {
    h = bf16_rtne(x);
    l = bf16_rtne(x - bf16_back(h));
}

struct Args {
    const float *fea, *pos, *pe_w1, *pe_b1, *pe_w2, *pe_b2;
    const float *sm_w1, *sm_b1, *sm_w2, *sm_b2, *diff_wts, *diff_bias, *gconv;
    unsigned short *MIX2H, *MIX2L, *WpTH, *WpTL, *SW1TH, *SW1TL, *GBTH, *GBTL;
    unsigned short *W1pTH, *W1pTL, *W2pTH, *W2pTL;
    float *b1p, *b2p;
    unsigned short *CATH, *CATL;
    float *out;
};

// =================== shared GEMM core: 64x64 tile, pre-split bf16 hi/lo operands ===================
__device__ __forceinline__ void gemm_core(
    const unsigned short* __restrict__ AH, const unsigned short* __restrict__ AL, int lda,
    const unsigned short* __restrict__ BloH, const unsigned short* __restrict__ BloL,
    const unsigned short* __restrict__ BhiH, const unsigned short* __restrict__ BhiL,
    int splitK, int K, int row0, int col0,
    short (*Ah)[72], short (*Al)[72], short (*Bh)[72], short (*Bl)[72],
    f32x4 acc[2][2])
{
    const int tid  = threadIdx.x;
    const int l    = tid & 63;
    const int w    = tid >> 6;
    const int wm   = w >> 1, wn = w & 1;
    const int role = l & 15, g = l >> 4;
    const int sr   = tid >> 3;
    const int scg  = (tid & 7) * 8;

    short8 pAH[2], pAL[2], pBH[2], pBL[2];
    auto prefetch = [&](int k0) {
        const unsigned short *bH, *bL; int kk;
        if (k0 < splitK) { bH = BloH; bL = BloL; kk = k0; }
        else             { bH = BhiH; bL = BhiL; kk = k0 - splitK; }
        #pragma unroll
        for (int it = 0; it < 2; ++it) {
            int r = sr + it * 32;
            pAH[it] = *(const short8*)(AH + (size_t)(row0 + r) * lda + k0 + scg);
            pAL[it] = *(const short8*)(AL + (size_t)(row0 + r) * lda + k0 + scg);
            pBH[it] = *(const short8*)(bH + (size_t)(col0 + r) * 256 + kk + scg);
            pBL[it] = *(const short8*)(bL + (size_t)(col0 + r) * 256 + kk + scg);
        }
    };

    prefetch(0);
    const int nk = K >> 6;
    for (int kt = 0; kt < nk; ++kt) {
        #pragma unroll
        for (int it = 0; it < 2; ++it) {
            int r = sr + it * 32;
            *(short8*)&Ah[r][scg] = pAH[it];
            *(short8*)&Al[r][scg] = pAL[it];
            *(short8*)&Bh[r][scg] = pBH[it];
            *(short8*)&Bl[r][scg] = pBL[it];
        }
        __syncthreads();
        if (kt + 1 < nk) prefetch((kt + 1) << 6);
        #pragma unroll
        for (int ks = 0; ks < 2; ++ks) {
            short8 fah[2], fal[2], fbh[2], fbl[2];
            #pragma unroll
            for (int mt = 0; mt < 2; ++mt) {
                int r = wm * 32 + mt * 16 + role, c = ks * 32 + g * 8;
                fah[mt] = *(const short8*)&Ah[r][c];
                fal[mt] = *(const short8*)&Al[r][c];
            }
            #pragma unroll
            for (int nt = 0; nt < 2; ++nt) {
                int r = wn * 32 + nt * 16 + role, c = ks * 32 + g * 8;
                fbh[nt] = *(const short8*)&Bh[r][c];
                fbl[nt] = *(const short8*)&Bl[r][c];
            }
            #pragma unroll
            for (int mt = 0; mt < 2; ++mt)
                #pragma unroll
                for (int nt = 0; nt < 2; ++nt) {
                    acc[mt][nt] = __builtin_amdgcn_mfma_f32_16x16x32_bf16(fah[mt], fbh[nt], acc[mt][nt], 0, 0, 0);
                    acc[mt][nt] = __builtin_amdgcn_mfma_f32_16x16x32_bf16(fah[mt], fbl[nt], acc[mt][nt], 0, 0, 0);
                    acc[mt][nt] = __builtin_amdgcn_mfma_f32_16x16x32_bf16(fal[mt], fbh[nt], acc[mt][nt], 0, 0, 0);
                }
        }
        __syncthreads();
    }
}

// =================== P0 role (482 independent roles; each reads only original inputs) ===================
__device__ __forceinline__ void do_role(const Args& A, char* smbuf, int blk, int tid)
{
    if (blk < 256) {
        int r0 = blk * 16;
        #pragma unroll
        for (int i = 0; i < 4; ++i) {
            int q  = tid + i * 256;
            int r  = r0 + (q >> 6);
            int c4 = (q & 63) * 4;
            f32x4 v = *(const f32x4*)(A.fea + (size_t)r * 256 + c4);
            ushort4v h, lo;
            #pragma unroll
            for (int j = 0; j < 4; ++j) { unsigned short hh, ll; split2(v[j], hh, ll); h[j] = hh; lo[j] = ll; }
            *(ushort4v*)&A.MIX2H[(size_t)r * 512 + c4] = h;
            *(ushort4v*)&A.MIX2L[(size_t)r * 512 + c4] = lo;
        }
    } else if (blk < 320) {
        int t  = blk - 256;
        int grp = t >> 4, tt = t & 15;
        int tr = tt >> 2, tc = tt & 3;
        const float* src; unsigned short *dH, *dL; int ilv, ofs;
        if (grp == 0)      { src = A.pe_w1;         dH = A.WpTH;  dL = A.WpTL;  ilv = 1; ofs = 0; }
        else if (grp == 1) { src = A.pe_w1 + 65536; dH = A.WpTH;  dL = A.WpTL;  ilv = 1; ofs = 1; }
        else if (grp == 2) { src = A.sm_w1;         dH = A.SW1TH; dL = A.SW1TL; ilv = 0; ofs = 0; }
        else               { src = A.gconv + 65536; dH = A.GBTH;  dL = A.GBTL;  ilv = 0; ofs = 0; }
        float (*ts)[65] = (float (*)[65])smbuf;
        #pragma unroll
        for (int i = 0; i < 4; ++i) {
            int q = tid + i * 256;
            int r = q >> 4, c4 = (q & 15) * 4;
            f32x4 v = *(const f32x4*)(src + (size_t)(tr * 64 + r) * 256 + tc * 64 + c4);
            ts[r][c4 + 0] = v[0]; ts[r][c4 + 1] = v[1]; ts[r][c4 + 2] = v[2]; ts[r][c4 + 3] = v[3];
        }
        __syncthreads();
        #pragma unroll
        for (int i = 0; i < 4; ++i) {
            int q = tid + i * 256;
            int n = q >> 4, k4 = (q & 15) * 4;
            ushort4v h, lo;
            #pragma unroll
            for (int j = 0; j < 4; ++j) { unsigned short hh, ll; split2(ts[k4 + j][n], hh, ll); h[j] = hh; lo[j] = ll; }
            int srcN   = tc * 64 + n;
            int dstRow = ilv ? (2 * srcN + ofs) : srcN;
            *(ushort4v*)&dH[(size_t)dstRow * 256 + tr * 64 + k4] = h;
            *(ushort4v*)&dL[(size_t)dstRow * 256 + tr * 64 + k4] = lo;
        }
    } else if (blk < 322) {
        int j = tid;
        if (blk == 320) {
            float s = 0.f;
            for (int k = 0; k < 256; ++k) s = fmaf(A.pe_b2[k], A.sm_w1[(size_t)(256 + k) * 256 + j], s);
            A.b1p[j] = s * (float)Pk + A.sm_b1[j];
        } else {
            float s = 0.f;
            for (int k = 0; k < 256; ++k) s = fmaf(A.sm_b2[k], A.gconv[(size_t)k * 256 + j], s);
            A.b2p[j] = s;
        }
    } else if (blk < 354) {
        int u = blk - 322;
        int z = u >> 4, tt = u & 15;
        int row0 = (tt >> 2) * 64, col0 = (tt & 3) * 64;
        const float* Af; const float* Bf; unsigned short *dH, *dL;
        if (z == 0) { Af = A.pe_w2; Bf = A.sm_w1 + 65536; dH = A.W1pTH; dL = A.W1pTL; }
        else        { Af = A.sm_w2; Bf = A.gconv;         dH = A.W2pTH; dL = A.W2pTL; }
        short (*Ah)[72] = (short (*)[72])(smbuf);
        short (*Al)[72] = (short (*)[72])(smbuf + 9216);
        short (*Bh)[72] = (short (*)[72])(smbuf + 18432);
        short (*Bl)[72] = (short (*)[72])(smbuf + 27648);
        const int l = tid & 63, w = tid >> 6, wm = w >> 1, wn = w & 1, role = l & 15, g = l >> 4;
        const int ar = tid >> 2, ac = (tid & 3) << 4;
        const int bc = (tid & 15) << 2, bk = (tid >> 4) << 2;
        f32x4 acc[2][2];
        #pragma unroll
        for (int i = 0; i < 2; ++i)
            #pragma unroll
            for (int j = 0; j < 2; ++j) acc[i][j] = (f32x4){0.f, 0.f, 0.f, 0.f};
        f32x4 aPf[4], bPf[4];
        auto load_tile = [&](int k0) {
            const float* Ap = Af + (size_t)(row0 + ar) * 256 + k0 + ac;
            #pragma unroll
            for (int j = 0; j < 4; ++j) aPf[j] = *(const f32x4*)(Ap + j * 4);
            #pragma unroll
            for (int jj = 0; jj < 4; ++jj)
                bPf[jj] = *(const f32x4*)(Bf + (size_t)(k0 + bk + jj) * 256 + col0 + bc);
        };
        load_tile(0);
        for (int kt = 0; kt < 4; ++kt) {
            {
                short8 h0, h1, l0, l1;
                #pragma unroll
                for (int j = 0; j < 4; ++j)
                    #pragma unroll
                    for (int e = 0; e < 4; ++e) {
                        unsigned short hh, ll; split2(aPf[j][e], hh, ll);
                        int idx = j * 4 + e;
                        if (idx < 8) { h0[idx] = (short)hh; l0[idx] = (short)ll; }
                        else         { h1[idx - 8] = (short)hh; l1[idx - 8] = (short)ll; }
                    }
                *(short8*)&Ah[ar][ac] = h0; *(short8*)&Ah[ar][ac + 8] = h1;
                *(short8*)&Al[ar][ac] = l0; *(short8*)&Al[ar][ac + 8] = l1;
                #pragma unroll
                for (int j = 0; j < 4; ++j) {
                    short4v h4, l4;
                    #pragma unroll
                    for (int jj = 0; jj < 4; ++jj) {
                        unsigned short hh, ll; split2(bPf[jj][j], hh, ll);
                        h4[jj] = (short)hh; l4[jj] = (short)ll;
                    }
                    *(short4v*)&Bh[bc + j][bk] = h4;
                    *(short4v*)&Bl[bc + j][bk] = l4;
                }
            }
            __syncthreads();
            if (kt + 1 < 4) load_tile((kt + 1) << 6);
            #pragma unroll
            for (int ks = 0; ks < 2; ++ks) {
                short8 fah[2], fal[2], fbh[2], fbl[2];
                #pragma unroll
                for (int mt = 0; mt < 2; ++mt) {
                    int r = wm * 32 + mt * 16 + role, c = ks * 32 + g * 8;
                    fah[mt] = *(const short8*)&Ah[r][c];
                    fal[mt] = *(const short8*)&Al[r][c];
                }
                #pragma unroll
                for (int nt = 0; nt < 2; ++nt) {
                    int r = wn * 32 + nt * 16 + role, c = ks * 32 + g * 8;
                    fbh[nt] = *(const short8*)&Bh[r][c];
                    fbl[nt] = *(const short8*)&Bl[r][c];
                }
                #pragma unroll
                for (int mt = 0; mt < 2; ++mt)
                    #pragma unroll
                    for (int nt = 0; nt < 2; ++nt) {
                        acc[mt][nt] = __builtin_amdgcn_mfma_f32_16x16x32_bf16(fah[mt], fbh[nt], acc[mt][nt], 0, 0, 0);
                        acc[mt][nt] = __builtin_amdgcn_mfma_f32_16x16x32_bf16(fah[mt], fbl[nt], acc[mt][nt], 0, 0, 0);
                        acc[mt][nt] = __builtin_amdgcn_mfma_f32_16x16x32_bf16(fal[mt], fbh[nt], acc[mt][nt], 0, 0, 0);
                    }
            }
            __syncthreads();
        }
        #pragma unroll
        for (int mt = 0; mt < 2; ++mt)
            #pragma unroll
            for (int nt = 0; nt < 2; ++nt) {
                int col = col0 + wn * 32 + nt * 16 + role;
                #pragma unroll
                for (int r = 0; r < 4; ++r) {
                    int row = row0 + wm * 32 + mt * 16 + g * 4 + r;
                    unsigned short hh, ll; split2(acc[mt][nt][r], hh, ll);
                    dH[(size_t)col * 256 + row] = hh;
                    dL[(size_t)col * 256 + row] = ll;
                }
            }
    } else {
        int b = blk - 354;
        float (*fs)[260] = (float (*)[260])(smbuf);
        float (*dwT)[32] = (float (*)[32])(smbuf + 33280);
        float (*wm_)[33] = (float (*)[33])(smbuf + 66048);
        const float* fb = A.fea + (size_t)b * 8192;
        #pragma unroll
        for (int i = 0; i < 8; ++i) {
            int q = tid + i * 256;
            int r = q >> 6, c4 = (q & 63) << 2;
            f32x4 v = *(const f32x4*)(fb + r * 256 + c4);
            fs[r][c4 + 0] = v[0]; fs[r][c4 + 1] = v[1]; fs[r][c4 + 2] = v[2]; fs[r][c4 + 3] = v[3];
        }
        {
            int p2 = tid & 31, kq = tid >> 5;
            #pragma unroll
            for (int i = 0; i < 8; ++i) {
                int c4 = ((kq << 3) + i) << 2;
                f32x4 v = *(const f32x4*)(A.diff_wts + (size_t)p2 * 256 + c4);
                dwT[c4 + 0][p2] = v[0]; dwT[c4 + 1][p2] = v[1];
                dwT[c4 + 2][p2] = v[2]; dwT[c4 + 3][p2] = v[3];
            }
        }
        __syncthreads();
        {
            const int p1 = tid >> 3, p2b = (tid & 7) << 2;
            f32x4 s = {0.f, 0.f, 0.f, 0.f};
            for (int k4 = 0; k4 < 256; k4 += 4) {
                f32x4 fv = *(const f32x4*)&fs[p1][k4];
                #pragma unroll
                for (int e = 0; e < 4; ++e) {
                    f32x4 dv = *(const f32x4*)&dwT[k4 + e][p2b];
                    s[0] = fmaf(fv[e], dv[0], s[0]);
                    s[1] = fmaf(fv[e], dv[1], s[1]);
                    s[2] = fmaf(fv[e], dv[2], s[2]);
                    s[3] = fmaf(fv[e], dv[3], s[3]);
                }
            }
            #pragma unroll
            for (int j = 0; j < 4; ++j) wm_[p1][p2b + j] = s[j] + A.diff_bias[p2b + j];
        }
        __syncthreads();
        if (tid < 32) {
            float m = wm_[tid][0];
            #pragma unroll
            for (int j = 1; j < 32; ++j) m = fmaxf(m, wm_[tid][j]);
            float e[32]; float sum = 0.f;
            #pragma unroll
            for (int j = 0; j < 32; ++j) { e[j] = __expf(wm_[tid][j] - m); sum += e[j]; }
            float inv = 1.f / sum;
            #pragma unroll
            for (int j = 0; j < 32; ++j) wm_[tid][j] = e[j] * inv;
        }
        __syncthreads();
        float fv[32];
        #pragma unroll
        for (int p2 = 0; p2 < 32; ++p2) fv[p2] = fs[p2][tid];
        for (int p1 = 0; p1 < 32; ++p1) {
            float s = 0.f;
            #pragma unroll
            for (int p2 = 0; p2 < 32; ++p2) s = fmaf(wm_[p1][p2], fv[p2], s);
            float v = fv[p1] - s;
            unsigned short hh, ll; split2(v, hh, ll);
            size_t o = (size_t)(b * 32 + p1) * 512 + 256 + tid;
            A.CATH[o] = hh; A.CATL[o] = ll;
        }
    }
}

// =================== P1 tile: G1 + hsum (tile t in 0..511) ===================
__device__ __forceinline__ void do_g1(const Args& A, char* smbuf, int t, int tid)
{
    const int x = t & 7, y = t >> 3;
    short (*Ah)[72] = (short (*)[72])(smbuf);
    short (*Al)[72] = (short (*)[72])(smbuf + 9216);
    short (*Bh)[72] = (short (*)[72])(smbuf + 18432);
    short (*Bl)[72] = (short (*)[72])(smbuf + 27648);
    const int row0 = y * 64, col0 = x * 64;
    f32x4 acc[2][2];
    #pragma unroll
    for (int i = 0; i < 2; ++i)
        #pragma unroll
        for (int j = 0; j < 2; ++j) acc[i][j] = (f32x4){0.f, 0.f, 0.f, 0.f};

    gemm_core(A.MIX2H, A.MIX2L, 512, A.WpTH, A.WpTL, nullptr, nullptr, 1 << 30, 256,
              row0, col0, Ah, Al, Bh, Bl, acc);

    float (*ms)[68] = (float (*)[68])(smbuf);
    const int l = tid & 63, w = tid >> 6, wm = w >> 1, wn = w & 1, role = l & 15, g = l >> 4;
    #pragma unroll
    for (int mt = 0; mt < 2; ++mt)
        #pragma unroll
        for (int nt = 0; nt < 2; ++nt)
            #pragma unroll
            for (int r = 0; r < 4; ++r)
                ms[wm * 32 + mt * 16 + g * 4 + r][wn * 32 + nt * 16 + role] = acc[mt][nt][r];
    __syncthreads();

    const int dd = tid & 31, bloc = (tid >> 5) & 1, pg = tid >> 6;
    const float b1v = A.pe_b1[x * 32 + dd];
    float apre[8], sum[8];
    #pragma unroll
    for (int i = 0; i < 8; ++i) {
        apre[i] = ms[bloc * 32 + pg * 8 + i][2 * dd] + b1v;
        sum[i] = 0.f;
    }
    for (int p2 = 0; p2 < 32; ++p2) {
        float cv = ms[bloc * 32 + p2][2 * dd + 1];
        #pragma unroll
        for (int i = 0; i < 8; ++i) sum[i] += fmaxf(apre[i] + cv, 0.f);
    }
    const int colg = 256 + x * 32 + dd;
    #pragma unroll
    for (int i = 0; i < 8; ++i) {
        int rowg = (2 * y + bloc) * 32 + pg * 8 + i;
        unsigned short hh, ll; split2(sum[i], hh, ll);
        A.MIX2H[(size_t)rowg * 512 + colg] = hh;
        A.MIX2L[(size_t)rowg * 512 + colg] = ll;
    }
}

// =================== P2 tile: G3 (tile t in 0..255) ===================
__device__ __forceinline__ void do_g3(const Args& A, char* smbuf, int t, int tid)
{
    const int x = t & 3, y = t >> 2;
    short (*Ah)[72] = (short (*)[72])(smbuf);
    short (*Al)[72] = (short (*)[72])(smbuf + 9216);
    short (*Bh)[72] = (short (*)[72])(smbuf + 18432);
    short (*Bl)[72] = (short (*)[72])(smbuf + 27648);
    const int row0 = y * 64, col0 = x * 64;
    f32x4 acc[2][2];
    #pragma unroll
    for (int i = 0; i < 2; ++i)
        #pragma unroll
        for (int j = 0; j < 2; ++j) acc[i][j] = (f32x4){0.f, 0.f, 0.f, 0.f};

    gemm_core(A.MIX2H, A.MIX2L, 512, A.SW1TH, A.SW1TL, A.W1pTH, A.W1pTL, 256, 512,
              row0, col0, Ah, Al, Bh, Bl, acc);

    const int l = tid & 63, w = tid >> 6, wm = w >> 1, wn = w & 1, role = l & 15, g = l >> 4;
    float bv[2];
    #pragma unroll
    for (int nt = 0; nt < 2; ++nt) bv[nt] = A.b1p[col0 + wn * 32 + nt * 16 + role];
    #pragma unroll
    for (int mt = 0; mt < 2; ++mt)
        #pragma unroll
        for (int nt = 0; nt < 2; ++nt) {
            int col = col0 + wn * 32 + nt * 16 + role;
            #pragma unroll
            for (int r = 0; r < 4; ++r) {
                int row = row0 + wm * 32 + mt * 16 + g * 4 + r;
                float v = fmaxf(acc[mt][nt][r] + bv[nt], 0.f);
                unsigned short hh, ll; split2(v, hh, ll);
                A.CATH[(size_t)row * 512 + col] = hh;
                A.CATL[(size_t)row * 512 + col] = ll;
            }
        }
}

// =================== P3 tile: G5 + adjacency + relu (tile t in 0..255) ===================
__device__ __forceinline__ void do_g5(const Args& A, char* smbuf, int t, int tid)
{
    const int x = t & 3, y = t >> 2;
    short (*Ah)[72] = (short (*)[72])(smbuf);
    short (*Al)[72] = (short (*)[72])(smbuf + 9216);
    short (*Bh)[72] = (short (*)[72])(smbuf + 18432);
    short (*Bl)[72] = (short (*)[72])(smbuf + 27648);
    const int row0 = y * 64, col0 = x * 64;
    f32x4 acc[2][2];
    #pragma unroll
    for (int i = 0; i < 2; ++i)
        #pragma unroll
        for (int j = 0; j < 2; ++j) acc[i][j] = (f32x4){0.f, 0.f, 0.f, 0.f};

    gemm_core(A.CATH, A.CATL, 512, A.W2pTH, A.W2pTL, A.GBTH, A.GBTL, 256, 512,
              row0, col0, Ah, Al, Bh, Bl, acc);

    float (*ms)[68]  = (float (*)[68])(smbuf);
    float* px        = (float*)(smbuf + 17408);
    float* py        = (float*)(smbuf + 17664);
    float* dinv_     = (float*)(smbuf + 17920);
    float (*na)[33]  = (float (*)[33])(smbuf + 18176);
    float (*ot)[68]  = (float (*)[68])(smbuf + 26624);

    const int l = tid & 63, w = tid >> 6, wm = w >> 1, wn = w & 1, role = l & 15, g = l >> 4;
    float bv[2];
    #pragma unroll
    for (int nt = 0; nt < 2; ++nt) bv[nt] = A.b2p[col0 + wn * 32 + nt * 16 + role];
    #pragma unroll
    for (int mt = 0; mt < 2; ++mt)
        #pragma unroll
        for (int nt = 0; nt < 2; ++nt)
            #pragma unroll
            for (int r = 0; r < 4; ++r)
                ms[wm * 32 + mt * 16 + g * 4 + r][wn * 32 + nt * 16 + role] = acc[mt][nt][r] + bv[nt];

    const int b0 = 2 * y;
    if (tid < 64) {
        int bi = tid >> 5, pp = tid & 31;
        px[bi * 32 + pp] = A.pos[(size_t)(b0 + bi) * 64 + pp * 2 + 0];
        py[bi * 32 + pp] = A.pos[(size_t)(b0 + bi) * 64 + pp * 2 + 1];
    }
    __syncthreads();
    {
        int bi = tid >> 7, p1 = (tid >> 2) & 31, p2g = (tid & 3) * 8;
        #pragma unroll
        for (int j = 0; j < 8; ++j) {
            int p2 = p2g + j;
            float v;
            if (p1 == p2) v = 1.f;
            else {
                float dx = px[bi * 32 + p1] - px[bi * 32 + p2];
                float dy = py[bi * 32 + p1] - py[bi * 32 + p2];
                v = (sqrtf(dx * dx + dy * dy) < 1.5f) ? 1.f : 0.f;
            }
            na[bi * 32 + p1][p2] = v;
        }
    }
    __syncthreads();
    if (tid < 64) {
        float s = 0.f;
        #pragma unroll
        for (int j = 0; j < 32; ++j) s += na[tid][j];
        dinv_[tid] = 1.f / sqrtf(s + 1e-6f);
    }
    __syncthreads();
    {
        int bi = tid >> 7, p1 = (tid >> 2) & 31, p2g = (tid & 3) * 8;
        #pragma unroll
        for (int j = 0; j < 8; ++j) {
            int p2 = p2g + j;
            na[bi * 32 + p1][p2] *= dinv_[bi * 32 + p1] * dinv_[bi * 32 + p2];
        }
    }
    __syncthreads();
    {
        const int p1 = tid & 31, bi = (tid >> 5) & 1, fg = (tid >> 6) * 16;
        f32x4 s4[4];
        #pragma unroll
        for (int j = 0; j < 4; ++j) s4[j] = (f32x4){0.f, 0.f, 0.f, 0.f};
        for (int p2 = 0; p2 < 32; ++p2) {
            float nv = na[bi * 32 + p1][p2];
            const f32x4* mrow = (const f32x4*)&ms[bi * 32 + p2][fg];
            #pragma unroll
            for (int j = 0; j < 4; ++j) {
                f32x4 mv = mrow[j];
                s4[j][0] = fmaf(nv, mv[0], s4[j][0]);
                s4[j][1] = fmaf(nv, mv[1], s4[j][1]);
                s4[j][2] = fmaf(nv, mv[2], s4[j][2]);
                s4[j][3] = fmaf(nv, mv[3], s4[j][3]);
            }
        }
        #pragma unroll
        for (int j = 0; j < 4; ++j)
            #pragma unroll
            for (int e = 0; e < 4; ++e)
                ot[bi * 32 + p1][fg + j * 4 + e] = s4[j][e];
    }
    __syncthreads();
    #pragma unroll
    for (int i = 0; i < 16; ++i) {
        int q = tid + i * 256;
        int row = q >> 6, f = q & 63;
        A.out[(size_t)(b0 * 32 + row) * 256 + col0 + f] = fmaxf(ot[row][f], 0.f);
    }
}

// =================== mega kernel: mode<0 = fully fused (cooperative, 256 blocks) ===================
// mode 0..3 = single phase (regular launch fallback, 256 blocks each)
__global__ __launch_bounds__(256, 2)
void mega_kernel(Args A, int mode)
{
    __shared__ __align__(16) char smbuf[70272];
    const int bid = blockIdx.x;
    const int tid = threadIdx.x;

    if (mode < 0) {
        cg::grid_group grid = cg::this_grid();
        for (int r = bid; r < 482; r += 256) {
            if (r != bid) __syncthreads();
            do_role(A, smbuf, r, tid);
        }
        grid.sync();
        do_g1(A, smbuf, bid, tid);
        __syncthreads();
        do_g1(A, smbuf, bid + 256, tid);
        grid.sync();
        do_g3(A, smbuf, bid, tid);
        grid.sync();
        do_g5(A, smbuf, bid, tid);
    } else if (mode == 0) {
        for (int r = bid; r < 482; r += 256) {
            if (r != bid) __syncthreads();
            do_role(A, smbuf, r, tid);
        }
    } else if (mode == 1) {
        do_g1(A, smbuf, bid, tid);
        __syncthreads();
        do_g1(A, smbuf, bid + 256, tid);
    } else if (mode == 2) {
        do_g3(A, smbuf, bid, tid);
    } else {
        do_g5(A, smbuf, bid, tid);
    }
}

extern "C" void kernel_launch(void* const* d_in, const int* in_sizes, int n_in,
                              void* d_out, int out_size, void* d_ws, size_t ws_size,
                              hipStream_t stream)
{
    char* ws = (char*)d_ws;

    Args a;
    a.fea       = (const float*)d_in[0];
    a.pos       = (const float*)d_in[1];
    a.pe_w1     = (const float*)d_in[2];
    a.pe_b1     = (const float*)d_in[3];
    a.pe_w2     = (const float*)d_in[4];
    a.pe_b2     = (const float*)d_in[5];
    a.sm_w1     = (const float*)d_in[6];
    a.sm_b1     = (const float*)d_in[7];
    a.sm_w2     = (const float*)d_in[8];
    a.sm_b2     = (const float*)d_in[9];
    a.diff_wts  = (const float*)d_in[10];
    a.diff_bias = (const float*)d_in[11];
    a.gconv     = (const float*)d_in[12];
    a.out       = (float*)d_out;

    a.MIX2H = (unsigned short*)(ws + 0);
    a.MIX2L = (unsigned short*)(ws + 4194304);
    a.CATH  = (unsigned short*)(ws + 8388608);
    a.CATL  = (unsigned short*)(ws + 12582912);
    a.WpTH  = (unsigned short*)(ws + 16777216);
    a.WpTL  = (unsigned short*)(ws + 17039360);
    a.SW1TH = (unsigned short*)(ws + 17301504);
    a.SW1TL = (unsigned short*)(ws + 17432576);
    a.GBTH  = (unsigned short*)(ws + 17563648);
    a.GBTL  = (unsigned short*)(ws + 17694720);
    a.W1pTH = (unsigned short*)(ws + 17825792);
    a.W1pTL = (unsigned short*)(ws + 17956864);
    a.W2pTH = (unsigned short*)(ws + 18087936);
    a.W2pTL = (unsigned short*)(ws + 18219008);
    a.b1p   = (float*)(ws + 18350080);
    a.b2p   = (float*)(ws + 18351104);

    int mode = -1;
    void* kargs[] = { (void*)&a, (void*)&mode };
    hipError_t e = hipLaunchCooperativeKernel((const void*)mega_kernel,
                                              dim3(256), dim3(256), kargs, 0, stream);
    if (e != hipSuccess) {
        (void)hipGetLastError();   // clear error state; fall back to 4 regular launches
        mega_kernel<<<256, 256, 0, stream>>>(a, 0);
        mega_kernel<<<256, 256, 0, stream>>>(a, 1);
        mega_kernel<<<256, 256, 0, stream>>>(a, 2);
        mega_kernel<<<256, 256, 0, stream>>>(a, 3);
    }
}

// Round 12
// 128.291 us; speedup vs baseline: 1.9216x; 1.9216x over previous
//
#include <hip/hip_runtime.h>
#include <math.h>

#define Dk 256
#define Pk 32
#define Bk 128

using f32x4    = __attribute__((ext_vector_type(4))) float;
using short8   = __attribute__((ext_vector_type(8))) short;
using short4v  = __attribute__((ext_vector_type(4))) short;
using ushort4v = __attribute__((ext_vector_type(4))) unsigned short;

static __device__ __forceinline__ unsigned short bf16_rtne(float x) {
    unsigned u = __float_as_uint(x);
    return (unsigned short)((u + 0x7fffu + ((u >> 16) & 1u)) >> 16);
}
static __device__ __forceinline__ float bf16_back(unsigned short h) {
    return __uint_as_float(((unsigned)h) << 16);
}
static __device__ __forceinline__ void split2(float x, unsigned short& h, unsigned short& l) {
    h = bf16_rtne(x);
    l = bf16_rtne(x - bf16_back(h));
}

// =================== shared GEMM core: 64x64 tile, pre-split bf16 hi/lo operands ===================
// A [M,K] hi/lo row-major (lda shorts). B given K-TRANSPOSED: BT[n][k] (ld 256 shorts);
// k<splitK from BloT, k>=splitK from BhiT (k-offset rebased). BK=64, reg-prefetch next tile.
__device__ __forceinline__ void gemm_core(
    const unsigned short* __restrict__ AH, const unsigned short* __restrict__ AL, int lda,
    const unsigned short* __restrict__ BloH, const unsigned short* __restrict__ BloL,
    const unsigned short* __restrict__ BhiH, const unsigned short* __restrict__ BhiL,
    int splitK, int K, int row0, int col0,
    short (*Ah)[72], short (*Al)[72], short (*Bh)[72], short (*Bl)[72],
    f32x4 acc[2][2])
{
    const int tid  = threadIdx.x;
    const int l    = tid & 63;
    const int w    = tid >> 6;
    const int wm   = w >> 1, wn = w & 1;
    const int role = l & 15, g = l >> 4;
    const int sr   = tid >> 3;          // staging row 0..31 (+32 on iter 1)
    const int scg  = (tid & 7) * 8;     // staging col group (shorts)

    short8 pAH[2], pAL[2], pBH[2], pBL[2];
    auto prefetch = [&](int k0) {
        const unsigned short *bH, *bL; int kk;
        if (k0 < splitK) { bH = BloH; bL = BloL; kk = k0; }
        else             { bH = BhiH; bL = BhiL; kk = k0 - splitK; }
        #pragma unroll
        for (int it = 0; it < 2; ++it) {
            int r = sr + it * 32;
            pAH[it] = *(const short8*)(AH + (size_t)(row0 + r) * lda + k0 + scg);
            pAL[it] = *(const short8*)(AL + (size_t)(row0 + r) * lda + k0 + scg);
            pBH[it] = *(const short8*)(bH + (size_t)(col0 + r) * 256 + kk + scg);
            pBL[it] = *(const short8*)(bL + (size_t)(col0 + r) * 256 + kk + scg);
        }
    };

    prefetch(0);
    const int nk = K >> 6;
    for (int kt = 0; kt < nk; ++kt) {
        #pragma unroll
        for (int it = 0; it < 2; ++it) {
            int r = sr + it * 32;
            *(short8*)&Ah[r][scg] = pAH[it];
            *(short8*)&Al[r][scg] = pAL[it];
            *(short8*)&Bh[r][scg] = pBH[it];
            *(short8*)&Bl[r][scg] = pBL[it];
        }
        __syncthreads();
        if (kt + 1 < nk) prefetch((kt + 1) << 6);
        #pragma unroll
        for (int ks = 0; ks < 2; ++ks) {
            short8 fah[2], fal[2], fbh[2], fbl[2];
            #pragma unroll
            for (int mt = 0; mt < 2; ++mt) {
                int r = wm * 32 + mt * 16 + role, c = ks * 32 + g * 8;
                fah[mt] = *(const short8*)&Ah[r][c];
                fal[mt] = *(const short8*)&Al[r][c];
            }
            #pragma unroll
            for (int nt = 0; nt < 2; ++nt) {
                int r = wn * 32 + nt * 16 + role, c = ks * 32 + g * 8;
                fbh[nt] = *(const short8*)&Bh[r][c];
                fbl[nt] = *(const short8*)&Bl[r][c];
            }
            #pragma unroll
            for (int mt = 0; mt < 2; ++mt)
                #pragma unroll
                for (int nt = 0; nt < 2; ++nt) {
                    acc[mt][nt] = __builtin_amdgcn_mfma_f32_16x16x32_bf16(fah[mt], fbh[nt], acc[mt][nt], 0, 0, 0);
                    acc[mt][nt] = __builtin_amdgcn_mfma_f32_16x16x32_bf16(fah[mt], fbl[nt], acc[mt][nt], 0, 0, 0);
                    acc[mt][nt] = __builtin_amdgcn_mfma_f32_16x16x32_bf16(fal[mt], fbh[nt], acc[mt][nt], 0, 0, 0);
                }
        }
        __syncthreads();
    }
}

// =================== PREP mega-kernel (one dispatch, block-range roles) ===================
// blk 0..255   : fea -> MIX2H/L[:, :256] (bf16 hi/lo, ld 512)
// blk 256..319 : weight transposes -> W'T (n-interleaved a/c!), SW1T, GBT (bf16 hi/lo)
// blk 320..321 : fused biases b1p, b2p (f32)
// blk 322..353 : W1pT = (pe_w2 @ sm_w1[256:])^T, W2pT = (sm_w2 @ gconv[:256])^T  (on-fly cvt GEMM)
// blk 354..481 : residual_diffs -> CATH/L[:, 256:512]
__global__ __launch_bounds__(256)
void prep_kernel(const float* __restrict__ fea, const float* __restrict__ pe_w1,
                 const float* __restrict__ pe_w2, const float* __restrict__ pe_b2,
                 const float* __restrict__ sm_w1, const float* __restrict__ sm_b1,
                 const float* __restrict__ sm_w2, const float* __restrict__ sm_b2,
                 const float* __restrict__ gconv,
                 const float* __restrict__ diff_wts, const float* __restrict__ diff_bias,
                 unsigned short* __restrict__ MIX2H, unsigned short* __restrict__ MIX2L,
                 unsigned short* __restrict__ WpTH,  unsigned short* __restrict__ WpTL,
                 unsigned short* __restrict__ SW1TH, unsigned short* __restrict__ SW1TL,
                 unsigned short* __restrict__ GBTH,  unsigned short* __restrict__ GBTL,
                 unsigned short* __restrict__ W1pTH, unsigned short* __restrict__ W1pTL,
                 unsigned short* __restrict__ W2pTH, unsigned short* __restrict__ W2pTL,
                 float* __restrict__ b1p, float* __restrict__ b2p,
                 unsigned short* __restrict__ CATH, unsigned short* __restrict__ CATL)
{
    __shared__ __align__(16) char smbuf[70272];
    const int blk = blockIdx.x;
    const int tid = threadIdx.x;

    if (blk < 256) {
        int r0 = blk * 16;
        #pragma unroll
        for (int i = 0; i < 4; ++i) {
            int q  = tid + i * 256;
            int r  = r0 + (q >> 6);
            int c4 = (q & 63) * 4;
            f32x4 v = *(const f32x4*)(fea + (size_t)r * 256 + c4);
            ushort4v h, lo;
            #pragma unroll
            for (int j = 0; j < 4; ++j) { unsigned short hh, ll; split2(v[j], hh, ll); h[j] = hh; lo[j] = ll; }
            *(ushort4v*)&MIX2H[(size_t)r * 512 + c4] = h;
            *(ushort4v*)&MIX2L[(size_t)r * 512 + c4] = lo;
        }
    } else if (blk < 320) {
        int t  = blk - 256;
        int grp = t >> 4, tt = t & 15;
        int tr = tt >> 2, tc = tt & 3;
        const float* src; unsigned short *dH, *dL; int ilv, ofs;
        if (grp == 0)      { src = pe_w1;         dH = WpTH;  dL = WpTL;  ilv = 1; ofs = 0; }
        else if (grp == 1) { src = pe_w1 + 65536; dH = WpTH;  dL = WpTL;  ilv = 1; ofs = 1; }
        else if (grp == 2) { src = sm_w1;         dH = SW1TH; dL = SW1TL; ilv = 0; ofs = 0; }
        else               { src = gconv + 65536; dH = GBTH;  dL = GBTL;  ilv = 0; ofs = 0; }
        float (*ts)[65] = (float (*)[65])smbuf;
        #pragma unroll
        for (int i = 0; i < 4; ++i) {
            int q = tid + i * 256;
            int r = q >> 4, c4 = (q & 15) * 4;
            f32x4 v = *(const f32x4*)(src + (size_t)(tr * 64 + r) * 256 + tc * 64 + c4);
            ts[r][c4 + 0] = v[0]; ts[r][c4 + 1] = v[1]; ts[r][c4 + 2] = v[2]; ts[r][c4 + 3] = v[3];
        }
        __syncthreads();
        #pragma unroll
        for (int i = 0; i < 4; ++i) {
            int q = tid + i * 256;
            int n = q >> 4, k4 = (q & 15) * 4;
            ushort4v h, lo;
            #pragma unroll
            for (int j = 0; j < 4; ++j) { unsigned short hh, ll; split2(ts[k4 + j][n], hh, ll); h[j] = hh; lo[j] = ll; }
            int srcN   = tc * 64 + n;
            int dstRow = ilv ? (2 * srcN + ofs) : srcN;
            *(ushort4v*)&dH[(size_t)dstRow * 256 + tr * 64 + k4] = h;
            *(ushort4v*)&dL[(size_t)dstRow * 256 + tr * 64 + k4] = lo;
        }
    } else if (blk < 322) {
        int j = tid;
        if (blk == 320) {
            float s = 0.f;
            for (int k = 0; k < 256; ++k) s = fmaf(pe_b2[k], sm_w1[(size_t)(256 + k) * 256 + j], s);
            b1p[j] = s * (float)Pk + sm_b1[j];
        } else {
            float s = 0.f;
            for (int k = 0; k < 256; ++k) s = fmaf(sm_b2[k], gconv[(size_t)k * 256 + j], s);
            b2p[j] = s;
        }
    } else if (blk < 354) {
        int u = blk - 322;
        int z = u >> 4, tt = u & 15;
        int row0 = (tt >> 2) * 64, col0 = (tt & 3) * 64;
        const float* Af; const float* Bf; unsigned short *dH, *dL;
        if (z == 0) { Af = pe_w2; Bf = sm_w1 + 65536; dH = W1pTH; dL = W1pTL; }
        else        { Af = sm_w2; Bf = gconv;         dH = W2pTH; dL = W2pTL; }
        short (*Ah)[72] = (short (*)[72])(smbuf);
        short (*Al)[72] = (short (*)[72])(smbuf + 9216);
        short (*Bh)[72] = (short (*)[72])(smbuf + 18432);
        short (*Bl)[72] = (short (*)[72])(smbuf + 27648);
        const int l = tid & 63, w = tid >> 6, wm = w >> 1, wn = w & 1, role = l & 15, g = l >> 4;
        const int ar = tid >> 2, ac = (tid & 3) << 4;
        const int bc = (tid & 15) << 2, bk = (tid >> 4) << 2;
        f32x4 acc[2][2];
        #pragma unroll
        for (int i = 0; i < 2; ++i)
            #pragma unroll
            for (int j = 0; j < 2; ++j) acc[i][j] = (f32x4){0.f, 0.f, 0.f, 0.f};
        f32x4 aPf[4], bPf[4];
        auto load_tile = [&](int k0) {
            const float* Ap = Af + (size_t)(row0 + ar) * 256 + k0 + ac;
            #pragma unroll
            for (int j = 0; j < 4; ++j) aPf[j] = *(const f32x4*)(Ap + j * 4);
            #pragma unroll
            for (int jj = 0; jj < 4; ++jj)
                bPf[jj] = *(const f32x4*)(Bf + (size_t)(k0 + bk + jj) * 256 + col0 + bc);
        };
        load_tile(0);
        for (int kt = 0; kt < 4; ++kt) {
            {
                short8 h0, h1, l0, l1;
                #pragma unroll
                for (int j = 0; j < 4; ++j)
                    #pragma unroll
                    for (int e = 0; e < 4; ++e) {
                        unsigned short hh, ll; split2(aPf[j][e], hh, ll);
                        int idx = j * 4 + e;
                        if (idx < 8) { h0[idx] = (short)hh; l0[idx] = (short)ll; }
                        else         { h1[idx - 8] = (short)hh; l1[idx - 8] = (short)ll; }
                    }
                *(short8*)&Ah[ar][ac] = h0; *(short8*)&Ah[ar][ac + 8] = h1;
                *(short8*)&Al[ar][ac] = l0; *(short8*)&Al[ar][ac + 8] = l1;
                #pragma unroll
                for (int j = 0; j < 4; ++j) {
                    short4v h4, l4;
                    #pragma unroll
                    for (int jj = 0; jj < 4; ++jj) {
                        unsigned short hh, ll; split2(bPf[jj][j], hh, ll);
                        h4[jj] = (short)hh; l4[jj] = (short)ll;
                    }
                    *(short4v*)&Bh[bc + j][bk] = h4;
                    *(short4v*)&Bl[bc + j][bk] = l4;
                }
            }
            __syncthreads();
            if (kt + 1 < 4) load_tile((kt + 1) << 6);
            #pragma unroll
            for (int ks = 0; ks < 2; ++ks) {
                short8 fah[2], fal[2], fbh[2], fbl[2];
                #pragma unroll
                for (int mt = 0; mt < 2; ++mt) {
                    int r = wm * 32 + mt * 16 + role, c = ks * 32 + g * 8;
                    fah[mt] = *(const short8*)&Ah[r][c];
                    fal[mt] = *(const short8*)&Al[r][c];
                }
                #pragma unroll
                for (int nt = 0; nt < 2; ++nt) {
                    int r = wn * 32 + nt * 16 + role, c = ks * 32 + g * 8;
                    fbh[nt] = *(const short8*)&Bh[r][c];
                    fbl[nt] = *(const short8*)&Bl[r][c];
                }
                #pragma unroll
                for (int mt = 0; mt < 2; ++mt)
                    #pragma unroll
                    for (int nt = 0; nt < 2; ++nt) {
                        acc[mt][nt] = __builtin_amdgcn_mfma_f32_16x16x32_bf16(fah[mt], fbh[nt], acc[mt][nt], 0, 0, 0);
                        acc[mt][nt] = __builtin_amdgcn_mfma_f32_16x16x32_bf16(fah[mt], fbl[nt], acc[mt][nt], 0, 0, 0);
                        acc[mt][nt] = __builtin_amdgcn_mfma_f32_16x16x32_bf16(fal[mt], fbh[nt], acc[mt][nt], 0, 0, 0);
                    }
            }
            __syncthreads();
        }
        #pragma unroll
        for (int mt = 0; mt < 2; ++mt)
            #pragma unroll
            for (int nt = 0; nt < 2; ++nt) {
                int col = col0 + wn * 32 + nt * 16 + role;
                #pragma unroll
                for (int r = 0; r < 4; ++r) {
                    int row = row0 + wm * 32 + mt * 16 + g * 4 + r;
                    unsigned short hh, ll; split2(acc[mt][nt][r], hh, ll);
                    dH[(size_t)col * 256 + row] = hh;     // transposed store
                    dL[(size_t)col * 256 + row] = ll;
                }
            }
    } else {
        int b = blk - 354;
        float (*fs)[260] = (float (*)[260])(smbuf);
        float (*dwT)[32] = (float (*)[32])(smbuf + 33280);
        float (*wm_)[33] = (float (*)[33])(smbuf + 66048);
        const float* fb = fea + (size_t)b * 8192;
        #pragma unroll
        for (int i = 0; i < 8; ++i) {
            int q = tid + i * 256;
            int r = q >> 6, c4 = (q & 63) << 2;
            f32x4 v = *(const f32x4*)(fb + r * 256 + c4);
            fs[r][c4 + 0] = v[0]; fs[r][c4 + 1] = v[1]; fs[r][c4 + 2] = v[2]; fs[r][c4 + 3] = v[3];
        }
        {
            int p2 = tid & 31, kq = tid >> 5;
            #pragma unroll
            for (int i = 0; i < 8; ++i) {
                int c4 = ((kq << 3) + i) << 2;
                f32x4 v = *(const f32x4*)(diff_wts + (size_t)p2 * 256 + c4);
                dwT[c4 + 0][p2] = v[0]; dwT[c4 + 1][p2] = v[1];
                dwT[c4 + 2][p2] = v[2]; dwT[c4 + 3][p2] = v[3];
            }
        }
        __syncthreads();
        {
            const int p1 = tid >> 3, p2b = (tid & 7) << 2;
            f32x4 s = {0.f, 0.f, 0.f, 0.f};
            for (int k4 = 0; k4 < 256; k4 += 4) {
                f32x4 fv = *(const f32x4*)&fs[p1][k4];
                #pragma unroll
                for (int e = 0; e < 4; ++e) {
                    f32x4 dv = *(const f32x4*)&dwT[k4 + e][p2b];
                    s[0] = fmaf(fv[e], dv[0], s[0]);
                    s[1] = fmaf(fv[e], dv[1], s[1]);
                    s[2] = fmaf(fv[e], dv[2], s[2]);
                    s[3] = fmaf(fv[e], dv[3], s[3]);
                }
            }
            #pragma unroll
            for (int j = 0; j < 4; ++j) wm_[p1][p2b + j] = s[j] + diff_bias[p2b + j];
        }
        __syncthreads();
        if (tid < 32) {
            float m = wm_[tid][0];
            #pragma unroll
            for (int j = 1; j < 32; ++j) m = fmaxf(m, wm_[tid][j]);
            float e[32]; float sum = 0.f;
            #pragma unroll
            for (int j = 0; j < 32; ++j) { e[j] = __expf(wm_[tid][j] - m); sum += e[j]; }
            float inv = 1.f / sum;
            #pragma unroll
            for (int j = 0; j < 32; ++j) wm_[tid][j] = e[j] * inv;
        }
        __syncthreads();
        float fv[32];
        #pragma unroll
        for (int p2 = 0; p2 < 32; ++p2) fv[p2] = fs[p2][tid];
        for (int p1 = 0; p1 < 32; ++p1) {
            float s = 0.f;
            #pragma unroll
            for (int p2 = 0; p2 < 32; ++p2) s = fmaf(wm_[p1][p2], fv[p2], s);
            float v = fv[p1] - s;          // fs[p1][tid] == fv[p1]
            unsigned short hh, ll; split2(v, hh, ll);
            size_t o = (size_t)(b * 32 + p1) * 512 + 256 + tid;
            CATH[o] = hh; CATL[o] = ll;
        }
    }
}

// =================== G1 + hsum fused ===================
__global__ __launch_bounds__(256)
void g1_hsum(const unsigned short* __restrict__ MIX2H, const unsigned short* __restrict__ MIX2L,
             const unsigned short* __restrict__ WpTH, const unsigned short* __restrict__ WpTL,
             const float* __restrict__ pe_b1,
             unsigned short* __restrict__ MH, unsigned short* __restrict__ ML)
{
    __shared__ __align__(16) char smbuf[36864];
    short (*Ah)[72] = (short (*)[72])(smbuf);
    short (*Al)[72] = (short (*)[72])(smbuf + 9216);
    short (*Bh)[72] = (short (*)[72])(smbuf + 18432);
    short (*Bl)[72] = (short (*)[72])(smbuf + 27648);
    const int row0 = blockIdx.y * 64, col0 = blockIdx.x * 64;
    f32x4 acc[2][2];
    #pragma unroll
    for (int i = 0; i < 2; ++i)
        #pragma unroll
        for (int j = 0; j < 2; ++j) acc[i][j] = (f32x4){0.f, 0.f, 0.f, 0.f};

    gemm_core(MIX2H, MIX2L, 512, WpTH, WpTL, nullptr, nullptr, 1 << 30, 256,
              row0, col0, Ah, Al, Bh, Bl, acc);

    float (*ms)[68] = (float (*)[68])(smbuf);
    const int tid = threadIdx.x;
    const int l = tid & 63, w = tid >> 6, wm = w >> 1, wn = w & 1, role = l & 15, g = l >> 4;
    #pragma unroll
    for (int mt = 0; mt < 2; ++mt)
        #pragma unroll
        for (int nt = 0; nt < 2; ++nt)
            #pragma unroll
            for (int r = 0; r < 4; ++r)
                ms[wm * 32 + mt * 16 + g * 4 + r][wn * 32 + nt * 16 + role] = acc[mt][nt][r];
    __syncthreads();

    const int dd = tid & 31, bloc = (tid >> 5) & 1, pg = tid >> 6;
    const float b1v = pe_b1[blockIdx.x * 32 + dd];
    float apre[8], sum[8];
    #pragma unroll
    for (int i = 0; i < 8; ++i) {
        apre[i] = ms[bloc * 32 + pg * 8 + i][2 * dd] + b1v;
        sum[i] = 0.f;
    }
    for (int p2 = 0; p2 < 32; ++p2) {
        float cv = ms[bloc * 32 + p2][2 * dd + 1];
        #pragma unroll
        for (int i = 0; i < 8; ++i) sum[i] += fmaxf(apre[i] + cv, 0.f);
    }
    const int colg = 256 + blockIdx.x * 32 + dd;
    #pragma unroll
    for (int i = 0; i < 8; ++i) {
        int rowg = (2 * blockIdx.y + bloc) * 32 + pg * 8 + i;
        unsigned short hh, ll; split2(sum[i], hh, ll);
        MH[(size_t)rowg * 512 + colg] = hh;
        ML[(size_t)rowg * 512 + colg] = ll;
    }
}

// =================== G3: t = relu(MIX2 @ [SW1;W1p] + b1p) -> CAT[:, :256] bf16 hi/lo ===================
__global__ __launch_bounds__(256)
void g3_kernel(const unsigned short* __restrict__ MIX2H, const unsigned short* __restrict__ MIX2L,
               const unsigned short* __restrict__ SW1TH, const unsigned short* __restrict__ SW1TL,
               const unsigned short* __restrict__ W1pTH, const unsigned short* __restrict__ W1pTL,
               const float* __restrict__ b1p,
               unsigned short* __restrict__ CATH, unsigned short* __restrict__ CATL)
{
    __shared__ __align__(16) char smbuf[36864];
    short (*Ah)[72] = (short (*)[72])(smbuf);
    short (*Al)[72] = (short (*)[72])(smbuf + 9216);
    short (*Bh)[72] = (short (*)[72])(smbuf + 18432);
    short (*Bl)[72] = (short (*)[72])(smbuf + 27648);
    const int row0 = blockIdx.y * 64, col0 = blockIdx.x * 64;
    f32x4 acc[2][2];
    #pragma unroll
    for (int i = 0; i < 2; ++i)
        #pragma unroll
        for (int j = 0; j < 2; ++j) acc[i][j] = (f32x4){0.f, 0.f, 0.f, 0.f};

    gemm_core(MIX2H, MIX2L, 512, SW1TH, SW1TL, W1pTH, W1pTL, 256, 512,
              row0, col0, Ah, Al, Bh, Bl, acc);

    const int tid = threadIdx.x;
    const int l = tid & 63, w = tid >> 6, wm = w >> 1, wn = w & 1, role = l & 15, g = l >> 4;
    float bv[2];
    #pragma unroll
    for (int nt = 0; nt < 2; ++nt) bv[nt] = b1p[col0 + wn * 32 + nt * 16 + role];
    #pragma unroll
    for (int mt = 0; mt < 2; ++mt)
        #pragma unroll
        for (int nt = 0; nt < 2; ++nt) {
            int col = col0 + wn * 32 + nt * 16 + role;
            #pragma unroll
            for (int r = 0; r < 4; ++r) {
                int row = row0 + wm * 32 + mt * 16 + g * 4 + r;
                float v = fmaxf(acc[mt][nt][r] + bv[nt], 0.f);
                unsigned short hh, ll; split2(v, hh, ll);
                CATH[(size_t)row * 512 + col] = hh;
                CATL[(size_t)row * 512 + col] = ll;
            }
        }
}

// =================== G5 + neighbor_mat + sync_gconv + relu fused ===================
__global__ __launch_bounds__(256)
void g5_adj(const unsigned short* __restrict__ CATH, const unsigned short* __restrict__ CATL,
            const unsigned short* __restrict__ W2pTH, const unsigned short* __restrict__ W2pTL,
            const unsigned short* __restrict__ GBTH, const unsigned short* __restrict__ GBTL,
            const float* __restrict__ b2p, const float* __restrict__ pos,
            float* __restrict__ out)
{
    __shared__ __align__(16) char smbuf[44032];
    short (*Ah)[72] = (short (*)[72])(smbuf);
    short (*Al)[72] = (short (*)[72])(smbuf + 9216);
    short (*Bh)[72] = (short (*)[72])(smbuf + 18432);
    short (*Bl)[72] = (short (*)[72])(smbuf + 27648);
    const int row0 = blockIdx.y * 64, col0 = blockIdx.x * 64;
    f32x4 acc[2][2];
    #pragma unroll
    for (int i = 0; i < 2; ++i)
        #pragma unroll
        for (int j = 0; j < 2; ++j) acc[i][j] = (f32x4){0.f, 0.f, 0.f, 0.f};

    gemm_core(CATH, CATL, 512, W2pTH, W2pTL, GBTH, GBTL, 256, 512,
              row0, col0, Ah, Al, Bh, Bl, acc);

    float (*ms)[68]  = (float (*)[68])(smbuf);            // 17408 B
    float* px        = (float*)(smbuf + 17408);
    float* py        = (float*)(smbuf + 17664);
    float* dinv_     = (float*)(smbuf + 17920);
    float (*na)[33]  = (float (*)[33])(smbuf + 18176);    // 8448 B
    float (*ot)[68]  = (float (*)[68])(smbuf + 26624);    // 17408 B -> 44032 total

    const int tid = threadIdx.x;
    const int l = tid & 63, w = tid >> 6, wm = w >> 1, wn = w & 1, role = l & 15, g = l >> 4;
    float bv[2];
    #pragma unroll
    for (int nt = 0; nt < 2; ++nt) bv[nt] = b2p[col0 + wn * 32 + nt * 16 + role];
    #pragma unroll
    for (int mt = 0; mt < 2; ++mt)
        #pragma unroll
        for (int nt = 0; nt < 2; ++nt)
            #pragma unroll
            for (int r = 0; r < 4; ++r)
                ms[wm * 32 + mt * 16 + g * 4 + r][wn * 32 + nt * 16 + role] = acc[mt][nt][r] + bv[nt];

    const int b0 = 2 * blockIdx.y;
    if (tid < 64) {
        int bi = tid >> 5, pp = tid & 31;
        px[bi * 32 + pp] = pos[(size_t)(b0 + bi) * 64 + pp * 2 + 0];
        py[bi * 32 + pp] = pos[(size_t)(b0 + bi) * 64 + pp * 2 + 1];
    }
    __syncthreads();
    {
        int bi = tid >> 7, p1 = (tid >> 2) & 31, p2g = (tid & 3) * 8;
        #pragma unroll
        for (int j = 0; j < 8; ++j) {
            int p2 = p2g + j;
            float v;
            if (p1 == p2) v = 1.f;
            else {
                float dx = px[bi * 32 + p1] - px[bi * 32 + p2];
                float dy = py[bi * 32 + p1] - py[bi * 32 + p2];
                v = (sqrtf(dx * dx + dy * dy) < 1.5f) ? 1.f : 0.f;
            }
            na[bi * 32 + p1][p2] = v;
        }
    }
    __syncthreads();
    if (tid < 64) {
        float s = 0.f;
        #pragma unroll
        for (int j = 0; j < 32; ++j) s += na[tid][j];
        dinv_[tid] = 1.f / sqrtf(s + 1e-6f);
    }
    __syncthreads();
    {
        int bi = tid >> 7, p1 = (tid >> 2) & 31, p2g = (tid & 3) * 8;
        #pragma unroll
        for (int j = 0; j < 8; ++j) {
            int p2 = p2g + j;
            na[bi * 32 + p1][p2] *= dinv_[bi * 32 + p1] * dinv_[bi * 32 + p2];
        }
    }
    __syncthreads();
    {
        const int p1 = tid & 31, bi = (tid >> 5) & 1, fg = (tid >> 6) * 16;
        f32x4 s4[4];
        #pragma unroll
        for (int j = 0; j < 4; ++j) s4[j] = (f32x4){0.f, 0.f, 0.f, 0.f};
        for (int p2 = 0; p2 < 32; ++p2) {
            float nv = na[bi * 32 + p1][p2];
            const f32x4* mrow = (const f32x4*)&ms[bi * 32 + p2][fg];
            #pragma unroll
            for (int j = 0; j < 4; ++j) {
                f32x4 mv = mrow[j];
                s4[j][0] = fmaf(nv, mv[0], s4[j][0]);
                s4[j][1] = fmaf(nv, mv[1], s4[j][1]);
                s4[j][2] = fmaf(nv, mv[2], s4[j][2]);
                s4[j][3] = fmaf(nv, mv[3], s4[j][3]);
            }
        }
        #pragma unroll
        for (int j = 0; j < 4; ++j)
            #pragma unroll
            for (int e = 0; e < 4; ++e)
                ot[bi * 32 + p1][fg + j * 4 + e] = s4[j][e];
    }
    __syncthreads();
    #pragma unroll
    for (int i = 0; i < 16; ++i) {
        int q = tid + i * 256;
        int row = q >> 6, f = q & 63;
        out[(size_t)(b0 * 32 + row) * 256 + col0 + f] = fmaxf(ot[row][f], 0.f);
    }
}

extern "C" void kernel_launch(void* const* d_in, const int* in_sizes, int n_in,
                              void* d_out, int out_size, void* d_ws, size_t ws_size,
                              hipStream_t stream)
{
    const float* fea       = (const float*)d_in[0];
    const float* pos       = (const float*)d_in[1];
    const float* pe_w1     = (const float*)d_in[2];
    const float* pe_b1     = (const float*)d_in[3];
    const float* pe_w2     = (const float*)d_in[4];
    const float* pe_b2     = (const float*)d_in[5];
    const float* sm_w1     = (const float*)d_in[6];
    const float* sm_b1     = (const float*)d_in[7];
    const float* sm_w2     = (const float*)d_in[8];
    const float* sm_b2     = (const float*)d_in[9];
    const float* diff_wts  = (const float*)d_in[10];
    const float* diff_bias = (const float*)d_in[11];
    const float* gconv     = (const float*)d_in[12];
    float* out = (float*)d_out;
    char*  ws  = (char*)d_ws;

    unsigned short* MIX2H = (unsigned short*)(ws + 0);          // [4096,512] 4 MB each
    unsigned short* MIX2L = (unsigned short*)(ws + 4194304);
    unsigned short* CATH  = (unsigned short*)(ws + 8388608);
    unsigned short* CATL  = (unsigned short*)(ws + 12582912);
    unsigned short* WpTH  = (unsigned short*)(ws + 16777216);   // [512,256] 256 KB
    unsigned short* WpTL  = (unsigned short*)(ws + 17039360);
    unsigned short* SW1TH = (unsigned short*)(ws + 17301504);   // [256,256] 128 KB each
    unsigned short* SW1TL = (unsigned short*)(ws + 17432576);
    unsigned short* GBTH  = (unsigned short*)(ws + 17563648);
    unsigned short* GBTL  = (unsigned short*)(ws + 17694720);
    unsigned short* W1pTH = (unsigned short*)(ws + 17825792);
    unsigned short* W1pTL = (unsigned short*)(ws + 17956864);
    unsigned short* W2pTH = (unsigned short*)(ws + 18087936);
    unsigned short* W2pTL = (unsigned short*)(ws + 18219008);
    float*          b1p   = (float*)(ws + 18350080);
    float*          b2p   = (float*)(ws + 18351104);

    // 1) prep: conversions + transposes + biases + weight-product GEMMs + diff
    prep_kernel<<<482, 256, 0, stream>>>(fea, pe_w1, pe_w2, pe_b2, sm_w1, sm_b1,
                                         sm_w2, sm_b2, gconv, diff_wts, diff_bias,
                                         MIX2H, MIX2L, WpTH, WpTL, SW1TH, SW1TL,
                                         GBTH, GBTL, W1pTH, W1pTL, W2pTH, W2pTL,
                                         b1p, b2p, CATH, CATL);
    // 2) G1 + hsum (a/c interleaved in B cols) -> MIX2[:, 256:]
    g1_hsum<<<dim3(8, 64), 256, 0, stream>>>(MIX2H, MIX2L, WpTH, WpTL, pe_b1, MIX2H, MIX2L);
    // 3) G3 -> CAT[:, :256]
    g3_kernel<<<dim3(4, 64), 256, 0, stream>>>(MIX2H, MIX2L, SW1TH, SW1TL, W1pTH, W1pTL,
                                               b1p, CATH, CATL);
    // 4) G5 + adjacency + relu -> out
    g5_adj<<<dim3(4, 64), 256, 0, stream>>>(CATH, CATL, W2pTH, W2pTL, GBTH, GBTL,
                                            b2p, pos, out);
}